// Round 1
// baseline (360.721 us; speedup 1.0000x reference)
//
#include <hip/hip_runtime.h>
#include <hip/hip_fp16.h>

#define NB 2
#define RAYS 4096
#define SAMP 96
#define CF 32
#define HID 64
#define HW 256

constexpr int RPB = 4;                 // rays per block
constexpr int THREADS = RPB * SAMP;    // 384

__device__ __forceinline__ float softplus_f(float z) {
    return fmaxf(z, 0.f) + __logf(1.f + __expf(-fabsf(z)));
}
__device__ __forceinline__ float sigmoid_f(float z) {
    return __fdividef(1.f, 1.f + __expf(-z));
}

// planes (N,3,C,H,W) f32  ->  pt (N*3, H, W, C) f16  (channel-interleaved)
__global__ __launch_bounds__(256)
void k_transpose(const float* __restrict__ src, __half2* __restrict__ dst) {
    int i = blockIdx.x * 256 + threadIdx.x;   // over 6*65536*16 half2 outputs
    int c2 = i & 15;
    int xy = (i >> 4) & 0xFFFF;
    int pn = i >> 20;                          // n*3+p  in [0,6)
    const float* s = src + (((size_t)(pn * CF + c2 * 2)) << 16) + xy;
    float a = s[0];
    float b = s[(size_t)1 << 16];
    dst[((size_t)(pn) << 16) * 16 + (size_t)xy * 16 + c2] = __floats2half2_rn(a, b);
}

template<bool USE_WS>
__global__ __launch_bounds__(THREADS)
void k_fused(const float* __restrict__ planes, const __half2* __restrict__ pt,
             const float* __restrict__ coords, const float* __restrict__ depths,
             const float* __restrict__ w1, const float* __restrict__ b1,
             const float* __restrict__ w2, const float* __restrict__ b2,
             float* __restrict__ out)
{
    __shared__ float w1T[CF * HID];        // [c][j]
    __shared__ float w2T[HID * 36];        // [j][o] padded to 36 (16B-aligned rows)
    __shared__ float b1s[HID];
    __shared__ float b2s[36];
    __shared__ __half2 rgbS[THREADS * 17]; // [sample][chan-pair], stride 17 (bank-friendly)
    __shared__ float sigS[THREADS];
    __shared__ float depS[THREADS];

    const int t = threadIdx.x;
    for (int i = t; i < CF * HID; i += THREADS) w1T[((i & 31) << 6) + (i >> 5)] = w1[i];
    for (int i = t; i < HID * 36; i += THREADS) {
        int j = i / 36, o = i - j * 36;
        w2T[i] = (o < 33) ? w2[o * HID + j] : 0.f;
    }
    if (t < HID) b1s[t] = b1[t];
    if (t < 36) b2s[t] = (t < 33) ? b2[t] : 0.f;
    __syncthreads();

    const int rl = t / SAMP;               // ray within block
    const int s  = t - rl * SAMP;          // sample along ray
    const int rayg = blockIdx.x * RPB + rl;    // n*4096 + ray
    const int n = rayg >> 12;
    const size_t m = (size_t)(rayg & (RAYS - 1)) * SAMP + s;
    const float* cp = coords + ((size_t)n * ((size_t)RAYS * SAMP) + m) * 3;
    const float c0 = cp[0], c1 = cp[1], c2 = cp[2];
    depS[t] = depths[(size_t)n * ((size_t)RAYS * SAMP) + m];

    __half2 acc[16];
    #pragma unroll
    for (int k = 0; k < 16; ++k) acc[k] = __float2half2_rn(0.f);
    float x[CF];
    #pragma unroll
    for (int c = 0; c < CF; ++c) x[c] = 0.f;

    #pragma unroll
    for (int p = 0; p < 3; ++p) {
        // projections: p0:(c0,c1)  p1:(c0,c2)  p2:(c2,c0)   (u->x/width, v->y/height)
        const float u = (p == 2) ? c2 : c0;
        const float v = (p == 0) ? c1 : ((p == 1) ? c2 : c0);
        const float xf = fmaf(u, 128.f, 127.5f);
        const float yf = fmaf(v, 128.f, 127.5f);
        const float x0f = floorf(xf), y0f = floorf(yf);
        const float wx = xf - x0f, wy = yf - y0f;
        const int x0 = (int)x0f, y0 = (int)y0f;
        const float vx0 = (x0 >= 0 && x0 < HW) ? 1.f : 0.f;
        const float vx1 = (x0 + 1 >= 0 && x0 + 1 < HW) ? 1.f : 0.f;
        const float vy0 = (y0 >= 0 && y0 < HW) ? 1.f : 0.f;
        const float vy1 = (y0 + 1 >= 0 && y0 + 1 < HW) ? 1.f : 0.f;
        const int xc0 = min(max(x0, 0), HW - 1), xc1 = min(max(x0 + 1, 0), HW - 1);
        const int yc0 = min(max(y0, 0), HW - 1), yc1 = min(max(y0 + 1, 0), HW - 1);
        const float w00 = (1.f - wx) * (1.f - wy) * vx0 * vy0;
        const float w10 = wx * (1.f - wy) * vx1 * vy0;
        const float w01 = (1.f - wx) * wy * vx0 * vy1;
        const float w11 = wx * wy * vx1 * vy1;

        if constexpr (USE_WS) {
            const __half2* pb = pt + ((size_t)(n * 3 + p) << 16) * 16;
            auto tap = [&](int yc, int xc, float w) {
                const float4* tp = (const float4*)(pb + (size_t)(yc * HW + xc) * 16);
                const __half2 wh = __float2half2_rn(w);
                #pragma unroll
                for (int q = 0; q < 4; ++q) {
                    union { float4 f; __half2 h[4]; } u4;
                    u4.f = tp[q];
                    acc[q * 4 + 0] = __hfma2(wh, u4.h[0], acc[q * 4 + 0]);
                    acc[q * 4 + 1] = __hfma2(wh, u4.h[1], acc[q * 4 + 1]);
                    acc[q * 4 + 2] = __hfma2(wh, u4.h[2], acc[q * 4 + 2]);
                    acc[q * 4 + 3] = __hfma2(wh, u4.h[3], acc[q * 4 + 3]);
                }
            };
            tap(yc0, xc0, w00);
            tap(yc0, xc1, w10);
            tap(yc1, xc0, w01);
            tap(yc1, xc1, w11);
        } else {
            const float* pb = planes + (((size_t)(n * 3 + p) * CF) << 16);
            const int i00 = yc0 * HW + xc0, i10 = yc0 * HW + xc1;
            const int i01 = yc1 * HW + xc0, i11 = yc1 * HW + xc1;
            #pragma unroll
            for (int c = 0; c < CF; ++c) {
                const float* pc = pb + ((size_t)c << 16);
                float a0 = fmaf(w00, pc[i00], fmaf(w10, pc[i10], 0.f));
                float a1 = fmaf(w01, pc[i01], fmaf(w11, pc[i11], 0.f));
                x[c] += a0 + a1;
            }
        }
    }

    if constexpr (USE_WS) {
        #pragma unroll
        for (int k = 0; k < 16; ++k) {
            float2 f = __half22float2(acc[k]);
            x[2 * k]     = f.x * (1.f / 3.f);
            x[2 * k + 1] = f.y * (1.f / 3.f);
        }
    } else {
        #pragma unroll
        for (int c = 0; c < CF; ++c) x[c] *= (1.f / 3.f);
    }

    // ---- layer 1: h = softplus(x @ w1T * 1/sqrt(32) + b1) ----
    float h[HID];
    #pragma unroll
    for (int j = 0; j < HID; ++j) h[j] = 0.f;
    #pragma unroll
    for (int c = 0; c < CF; ++c) {
        const float xc = x[c];
        const float4* row = (const float4*)&w1T[c << 6];
        #pragma unroll
        for (int j4 = 0; j4 < 16; ++j4) {
            float4 wv = row[j4];
            h[j4 * 4 + 0] = fmaf(xc, wv.x, h[j4 * 4 + 0]);
            h[j4 * 4 + 1] = fmaf(xc, wv.y, h[j4 * 4 + 1]);
            h[j4 * 4 + 2] = fmaf(xc, wv.z, h[j4 * 4 + 2]);
            h[j4 * 4 + 3] = fmaf(xc, wv.w, h[j4 * 4 + 3]);
        }
    }
    constexpr float is32 = 0.17677669529663687f;   // 1/sqrt(32)
    #pragma unroll
    for (int j = 0; j < HID; ++j) h[j] = softplus_f(fmaf(h[j], is32, b1s[j]));

    // ---- layer 2: out = h @ w2T * 1/8 + b2 ----
    float oa[36];
    #pragma unroll
    for (int o = 0; o < 36; ++o) oa[o] = 0.f;
    #pragma unroll
    for (int j = 0; j < HID; ++j) {
        const float hj = h[j];
        const float4* row = (const float4*)&w2T[j * 36];
        #pragma unroll
        for (int o4 = 0; o4 < 9; ++o4) {
            float4 wv = row[o4];
            oa[o4 * 4 + 0] = fmaf(hj, wv.x, oa[o4 * 4 + 0]);
            oa[o4 * 4 + 1] = fmaf(hj, wv.y, oa[o4 * 4 + 1]);
            oa[o4 * 4 + 2] = fmaf(hj, wv.z, oa[o4 * 4 + 2]);
            oa[o4 * 4 + 3] = fmaf(hj, wv.w, oa[o4 * 4 + 3]);
        }
    }
    #pragma unroll
    for (int o = 0; o < 33; ++o) oa[o] = fmaf(oa[o], 0.125f, b2s[o]);

    sigS[t] = oa[0];
    #pragma unroll
    for (int p = 0; p < 16; ++p) {
        float r0 = sigmoid_f(oa[1 + 2 * p]) * 1.002f - 0.001f;
        float r1 = sigmoid_f(oa[2 + 2 * p]) * 1.002f - 0.001f;
        rgbS[t * 17 + p] = __floats2half2_rn(r0, r1);
    }
    __syncthreads();

    // ---- composite: waves 0..1, half-wave per ray ----
    if (t < RPB * 32) {
        const int crl = t >> 5;
        const int c = t & 31;
        const int bs = crl * SAMP;
        float T = 1.f, a_out = 0.f;
        float sp = sigS[bs], dp = depS[bs];
        __half2 hv = rgbS[bs * 17 + (c >> 1)];
        float rp = (c & 1) ? __high2float(hv) : __low2float(hv);
        for (int ss = 1; ss < SAMP; ++ss) {
            float sc = sigS[bs + ss];
            float dc = depS[bs + ss];
            __half2 hv2 = rgbS[(bs + ss) * 17 + (c >> 1)];
            float rc = (c & 1) ? __high2float(hv2) : __low2float(hv2);
            float dens = softplus_f(0.5f * (sp + sc) - 1.f);
            float alpha = 1.f - __expf(-(dc - dp) * dens);
            a_out = fmaf(alpha * T, 0.5f * (rp + rc), a_out);
            T *= 1.f - alpha + 1e-10f;
            sp = sc; dp = dc; rp = rc;
        }
        out[(size_t)(blockIdx.x * RPB + crl) * CF + c] = fmaf(a_out, 2.f, -1.f);
    }
}

extern "C" void kernel_launch(void* const* d_in, const int* in_sizes, int n_in,
                              void* d_out, int out_size, void* d_ws, size_t ws_size,
                              hipStream_t stream) {
    (void)in_sizes; (void)n_in; (void)out_size;
    const float* planes = (const float*)d_in[0];
    const float* coords = (const float*)d_in[1];
    const float* depths = (const float*)d_in[2];
    const float* w1 = (const float*)d_in[3];
    const float* b1 = (const float*)d_in[4];
    const float* w2 = (const float*)d_in[5];
    const float* b2 = (const float*)d_in[6];
    float* out = (float*)d_out;

    const size_t need = (size_t)NB * 3 * HW * HW * CF * sizeof(__half);  // ~25.2 MB
    const int nblocks = NB * RAYS / RPB;   // 2048

    if (ws_size >= need) {
        __half2* pt = (__half2*)d_ws;
        const int tgrid = NB * 3 * HW * HW * CF / 2 / 256;   // 24576
        k_transpose<<<tgrid, 256, 0, stream>>>(planes, pt);
        k_fused<true><<<nblocks, THREADS, 0, stream>>>(planes, pt, coords, depths,
                                                       w1, b1, w2, b2, out);
    } else {
        k_fused<false><<<nblocks, THREADS, 0, stream>>>(planes, nullptr, coords, depths,
                                                        w1, b1, w2, b2, out);
    }
}

// Round 2
// 263.999 us; speedup vs baseline: 1.3664x; 1.3664x over previous
//
#include <hip/hip_runtime.h>
#include <hip/hip_fp16.h>

#define NB 2
#define RAYS 4096
#define SAMP 96
#define CF 32
#define HID 64
#define HW 256

constexpr int THREADS = 384;          // 4 rays * 96 samples, 6 waves
constexpr int SLICE = 9216;           // per-wave LDS slice (bytes)
constexpr int SIG_OFF = 5120;         // float[64]
constexpr int DEP_OFF = 5376;         // float[64]
// rgb:   row*80 + o*2   (o in 1..32), rows 0..63
// xS:    row*80 + c*16  (c chunk of 8 f16)
// hS:    row*144 + h*2  (h in 0..63)

typedef _Float16 f16x8 __attribute__((ext_vector_type(8)));
typedef float f32x4 __attribute__((ext_vector_type(4)));

__device__ __forceinline__ float softplus_f(float z) {
    return fmaxf(z, 0.f) + __logf(1.f + __expf(-fabsf(z)));
}
__device__ __forceinline__ float sigmoid_f(float z) {
    return __fdividef(1.f, 1.f + __expf(-z));
}

// planes (N,3,C,H,W) f32  ->  pt (N*3, H, W, C) f16  (channel-interleaved)
__global__ __launch_bounds__(256)
void k_transpose(const float* __restrict__ src, __half2* __restrict__ dst) {
    int i = blockIdx.x * 256 + threadIdx.x;   // over 6*65536*16 half2 outputs
    int c2 = i & 15;
    int xy = (i >> 4) & 0xFFFF;
    int pn = i >> 20;                          // n*3+p  in [0,6)
    const float* s = src + (((size_t)(pn * CF + c2 * 2)) << 16) + xy;
    float a = s[0];
    float b = s[(size_t)1 << 16];
    dst[((size_t)(pn) << 16) * 16 + (size_t)xy * 16 + c2] = __floats2half2_rn(a, b);
}

template<bool USE_WS>
__global__ __launch_bounds__(THREADS)
void k_fused(const float* __restrict__ planes, const __half2* __restrict__ pt,
             const float* __restrict__ coords, const float* __restrict__ depths,
             const float* __restrict__ w1, const float* __restrict__ b1,
             const float* __restrict__ w2, const float* __restrict__ b2,
             float* __restrict__ out)
{
    __shared__ __align__(16) char sm[6 * SLICE];
    const int t = threadIdx.x;
    const int wv = t >> 6;                 // wave id 0..5
    const int l = t & 63;                  // lane
    const int g = l >> 4;                  // lane group 0..3
    const int ln = l & 15;
    char* const slice = sm + wv * SLICE;

    const int msamp = blockIdx.x * THREADS + t;       // global sample id
    const int nb = (blockIdx.x >= (NB * RAYS / 4 / 2)) ? 1 : 0;  // batch (1024 blocks per batch)

    // ---- preload weight fragments into registers ----
    // layer1: B1[k][n] = w1[n][k], n = 16*Nt + ln, k = 8*g + i
    f16x8 b1f[4];
    float b1v[4];
    #pragma unroll
    for (int Nt = 0; Nt < 4; ++Nt) {
        const int hn = 16 * Nt + ln;
        const float4* p0 = (const float4*)(w1 + hn * CF + g * 8);
        float4 u = p0[0], v = p0[1];
        b1f[Nt][0] = (_Float16)u.x; b1f[Nt][1] = (_Float16)u.y;
        b1f[Nt][2] = (_Float16)u.z; b1f[Nt][3] = (_Float16)u.w;
        b1f[Nt][4] = (_Float16)v.x; b1f[Nt][5] = (_Float16)v.y;
        b1f[Nt][6] = (_Float16)v.z; b1f[Nt][7] = (_Float16)v.w;
        b1v[Nt] = b1[hn];
    }
    // layer2: B2[k][n] = w2[n][k], n = 16*Nt2 + ln (n<33 else 0), k = 32*kh + 8*g + i
    f16x8 b2f[3][2];
    float b2v[3];
    #pragma unroll
    for (int Nt2 = 0; Nt2 < 3; ++Nt2) {
        const int o = 16 * Nt2 + ln;
        if (o < 33) {
            #pragma unroll
            for (int kh = 0; kh < 2; ++kh) {
                const float4* p0 = (const float4*)(w2 + o * HID + kh * 32 + g * 8);
                float4 u = p0[0], v = p0[1];
                b2f[Nt2][kh][0] = (_Float16)u.x; b2f[Nt2][kh][1] = (_Float16)u.y;
                b2f[Nt2][kh][2] = (_Float16)u.z; b2f[Nt2][kh][3] = (_Float16)u.w;
                b2f[Nt2][kh][4] = (_Float16)v.x; b2f[Nt2][kh][5] = (_Float16)v.y;
                b2f[Nt2][kh][6] = (_Float16)v.z; b2f[Nt2][kh][7] = (_Float16)v.w;
            }
            b2v[Nt2] = b2[o];
        } else {
            #pragma unroll
            for (int kh = 0; kh < 2; ++kh)
                #pragma unroll
                for (int i = 0; i < 8; ++i) b2f[Nt2][kh][i] = (_Float16)0.f;
            b2v[Nt2] = 0.f;
        }
    }

    // ---- gather triplane features ----
    const float* cp = coords + (size_t)msamp * 3;
    const float c0 = cp[0], c1 = cp[1], c2v = cp[2];
    const float myDep = depths[msamp];

    __half2 acc[16];
    #pragma unroll
    for (int k = 0; k < 16; ++k) acc[k] = __float2half2_rn(0.f);
    float xf32[CF];
    if constexpr (!USE_WS) {
        #pragma unroll
        for (int c = 0; c < CF; ++c) xf32[c] = 0.f;
    }

    #pragma unroll
    for (int p = 0; p < 3; ++p) {
        const float u = (p == 2) ? c2v : c0;
        const float v = (p == 0) ? c1 : ((p == 1) ? c2v : c0);
        const float xf = fmaf(u, 128.f, 127.5f);
        const float yf = fmaf(v, 128.f, 127.5f);
        const float x0f = floorf(xf), y0f = floorf(yf);
        const float wx = xf - x0f, wy = yf - y0f;
        const int x0 = (int)x0f, y0 = (int)y0f;
        const float vx0 = (x0 >= 0 && x0 < HW) ? 1.f : 0.f;
        const float vx1 = (x0 + 1 >= 0 && x0 + 1 < HW) ? 1.f : 0.f;
        const float vy0 = (y0 >= 0 && y0 < HW) ? 1.f : 0.f;
        const float vy1 = (y0 + 1 >= 0 && y0 + 1 < HW) ? 1.f : 0.f;
        const int xc0 = min(max(x0, 0), HW - 1), xc1 = min(max(x0 + 1, 0), HW - 1);
        const int yc0 = min(max(y0, 0), HW - 1), yc1 = min(max(y0 + 1, 0), HW - 1);
        const float w00 = (1.f - wx) * (1.f - wy) * vx0 * vy0;
        const float w10 = wx * (1.f - wy) * vx1 * vy0;
        const float w01 = (1.f - wx) * wy * vx0 * vy1;
        const float w11 = wx * wy * vx1 * vy1;

        if constexpr (USE_WS) {
            const __half2* pb = pt + ((size_t)(nb * 3 + p) << 16) * 16;
            auto tap = [&](int yc, int xc, float w) {
                const float4* tp = (const float4*)(pb + (size_t)(yc * HW + xc) * 16);
                const __half2 wh = __float2half2_rn(w);
                #pragma unroll
                for (int q = 0; q < 4; ++q) {
                    union { float4 f; __half2 h[4]; } u4;
                    u4.f = tp[q];
                    acc[q * 4 + 0] = __hfma2(wh, u4.h[0], acc[q * 4 + 0]);
                    acc[q * 4 + 1] = __hfma2(wh, u4.h[1], acc[q * 4 + 1]);
                    acc[q * 4 + 2] = __hfma2(wh, u4.h[2], acc[q * 4 + 2]);
                    acc[q * 4 + 3] = __hfma2(wh, u4.h[3], acc[q * 4 + 3]);
                }
            };
            tap(yc0, xc0, w00);
            tap(yc0, xc1, w10);
            tap(yc1, xc0, w01);
            tap(yc1, xc1, w11);
        } else {
            const float* pb = planes + (((size_t)(nb * 3 + p) * CF) << 16);
            const int i00 = yc0 * HW + xc0, i10 = yc0 * HW + xc1;
            const int i01 = yc1 * HW + xc0, i11 = yc1 * HW + xc1;
            #pragma unroll
            for (int c = 0; c < CF; ++c) {
                const float* pc = pb + ((size_t)c << 16);
                float a0 = fmaf(w00, pc[i00], fmaf(w10, pc[i10], 0.f));
                float a1 = fmaf(w01, pc[i01], fmaf(w11, pc[i11], 0.f));
                xf32[c] += a0 + a1;
            }
        }
    }
    if constexpr (!USE_WS) {
        #pragma unroll
        for (int k = 0; k < 16; ++k)
            acc[k] = __floats2half2_rn(xf32[2 * k], xf32[2 * k + 1]);
    }

    // ---- stage x into per-wave LDS slice (rows = samples, stride 80B) ----
    const __half2 third = __float2half2_rn(1.f / 3.f);
    #pragma unroll
    for (int c = 0; c < 4; ++c) {
        union { __half2 h[4]; int4 v; } u4;
        #pragma unroll
        for (int j = 0; j < 4; ++j) u4.h[j] = __hmul2(acc[4 * c + j], third);
        *(int4*)(slice + l * 80 + c * 16) = u4.v;
    }

    // ---- layer 1 via MFMA: H[m][n] = X[m][k] * W1^T[k][n] ----
    // A-frag: m = ln, k = 8*g + i  (read own wave's rows)
    f16x8 a1[4];
    #pragma unroll
    for (int Mt = 0; Mt < 4; ++Mt)
        a1[Mt] = *(const f16x8*)(slice + (16 * Mt + ln) * 80 + g * 16);

    constexpr float is32 = 0.17677669529663687f;   // 1/sqrt(32)
    #pragma unroll
    for (int Nt = 0; Nt < 4; ++Nt) {
        f32x4 d0 = {0.f, 0.f, 0.f, 0.f};
        f32x4 d1 = {0.f, 0.f, 0.f, 0.f};
        f32x4 d2 = {0.f, 0.f, 0.f, 0.f};
        f32x4 d3 = {0.f, 0.f, 0.f, 0.f};
        d0 = __builtin_amdgcn_mfma_f32_16x16x32_f16(a1[0], b1f[Nt], d0, 0, 0, 0);
        d1 = __builtin_amdgcn_mfma_f32_16x16x32_f16(a1[1], b1f[Nt], d1, 0, 0, 0);
        d2 = __builtin_amdgcn_mfma_f32_16x16x32_f16(a1[2], b1f[Nt], d2, 0, 0, 0);
        d3 = __builtin_amdgcn_mfma_f32_16x16x32_f16(a1[3], b1f[Nt], d3, 0, 0, 0);
        const int hcol = 16 * Nt + ln;
        // D layout: col(n)=ln, row(m)=4*g+reg within tile
        #pragma unroll
        for (int Mt = 0; Mt < 4; ++Mt) {
            f32x4 dd = (Mt == 0) ? d0 : (Mt == 1) ? d1 : (Mt == 2) ? d2 : d3;
            #pragma unroll
            for (int r = 0; r < 4; ++r) {
                const float hv = softplus_f(fmaf(dd[r], is32, b1v[Nt]));
                const int row = 16 * Mt + 4 * g + r;
                *(__half*)(slice + row * 144 + hcol * 2) = __float2half(hv);
            }
        }
    }

    // ---- layer 2 via MFMA: O[m][n] = H[m][k] * W2^T[k][n] ----
    f16x8 a2[4][2];
    #pragma unroll
    for (int Mt = 0; Mt < 4; ++Mt)
        #pragma unroll
        for (int kh = 0; kh < 2; ++kh)
            a2[Mt][kh] = *(const f16x8*)(slice + (16 * Mt + ln) * 144 + (kh * 4 + g) * 16);

    // hS now dead (frags in regs) — safe to overwrite slice with rgb/sig/dep
    *(float*)(slice + DEP_OFF + l * 4) = myDep;

    #pragma unroll
    for (int Nt2 = 0; Nt2 < 3; ++Nt2) {
        f32x4 e0 = {0.f, 0.f, 0.f, 0.f};
        f32x4 e1 = {0.f, 0.f, 0.f, 0.f};
        f32x4 e2 = {0.f, 0.f, 0.f, 0.f};
        f32x4 e3 = {0.f, 0.f, 0.f, 0.f};
        #pragma unroll
        for (int kh = 0; kh < 2; ++kh) {
            e0 = __builtin_amdgcn_mfma_f32_16x16x32_f16(a2[0][kh], b2f[Nt2][kh], e0, 0, 0, 0);
            e1 = __builtin_amdgcn_mfma_f32_16x16x32_f16(a2[1][kh], b2f[Nt2][kh], e1, 0, 0, 0);
            e2 = __builtin_amdgcn_mfma_f32_16x16x32_f16(a2[2][kh], b2f[Nt2][kh], e2, 0, 0, 0);
            e3 = __builtin_amdgcn_mfma_f32_16x16x32_f16(a2[3][kh], b2f[Nt2][kh], e3, 0, 0, 0);
        }
        const int o = 16 * Nt2 + ln;
        if (o == 0) {
            #pragma unroll
            for (int Mt = 0; Mt < 4; ++Mt) {
                f32x4 ee = (Mt == 0) ? e0 : (Mt == 1) ? e1 : (Mt == 2) ? e2 : e3;
                #pragma unroll
                for (int r = 0; r < 4; ++r) {
                    const int row = 16 * Mt + 4 * g + r;
                    *(float*)(slice + SIG_OFF + row * 4) = fmaf(ee[r], 0.125f, b2v[0]);
                }
            }
        } else if (o < 33) {
            #pragma unroll
            for (int Mt = 0; Mt < 4; ++Mt) {
                f32x4 ee = (Mt == 0) ? e0 : (Mt == 1) ? e1 : (Mt == 2) ? e2 : e3;
                #pragma unroll
                for (int r = 0; r < 4; ++r) {
                    const float vv = fmaf(ee[r], 0.125f, b2v[Nt2]);
                    const float rr = sigmoid_f(vv) * 1.002f - 0.001f;
                    const int row = 16 * Mt + 4 * g + r;
                    *(__half*)(slice + row * 80 + o * 2) = __float2half(rr);
                }
            }
        }
    }

    __syncthreads();

    // ---- composite: threads 0..127, 32 channels x 4 rays ----
    if (t < 128) {
        const int crl = t >> 5;
        const int c = t & 31;
        const int bs = crl * SAMP;
        auto sigAt = [&](int sb) -> float {
            return *(const float*)(sm + (sb >> 6) * SLICE + SIG_OFF + (sb & 63) * 4);
        };
        auto depAt = [&](int sb) -> float {
            return *(const float*)(sm + (sb >> 6) * SLICE + DEP_OFF + (sb & 63) * 4);
        };
        auto rgbAt = [&](int sb) -> float {
            return __half2float(*(const __half*)(sm + (sb >> 6) * SLICE + (sb & 63) * 80 + (c + 1) * 2));
        };
        float T = 1.f, a_out = 0.f;
        float sp = sigAt(bs), dp = depAt(bs), rp = rgbAt(bs);
        for (int ss = 1; ss < SAMP; ++ss) {
            const float sc = sigAt(bs + ss);
            const float dc = depAt(bs + ss);
            const float rc = rgbAt(bs + ss);
            const float dens = softplus_f(0.5f * (sp + sc) - 1.f);
            const float alpha = 1.f - __expf(-(dc - dp) * dens);
            a_out = fmaf(alpha * T, 0.5f * (rp + rc), a_out);
            T *= 1.f - alpha + 1e-10f;
            sp = sc; dp = dc; rp = rc;
        }
        out[(size_t)(blockIdx.x * 4 + crl) * CF + c] = fmaf(a_out, 2.f, -1.f);
    }
}

extern "C" void kernel_launch(void* const* d_in, const int* in_sizes, int n_in,
                              void* d_out, int out_size, void* d_ws, size_t ws_size,
                              hipStream_t stream) {
    (void)in_sizes; (void)n_in; (void)out_size;
    const float* planes = (const float*)d_in[0];
    const float* coords = (const float*)d_in[1];
    const float* depths = (const float*)d_in[2];
    const float* w1 = (const float*)d_in[3];
    const float* b1 = (const float*)d_in[4];
    const float* w2 = (const float*)d_in[5];
    const float* b2 = (const float*)d_in[6];
    float* out = (float*)d_out;

    const size_t need = (size_t)NB * 3 * HW * HW * CF * sizeof(__half);  // ~25.2 MB
    const int nblocks = NB * RAYS * SAMP / THREADS;   // 2048

    if (ws_size >= need) {
        __half2* pt = (__half2*)d_ws;
        const int tgrid = NB * 3 * HW * HW * CF / 2 / 256;   // 24576
        k_transpose<<<tgrid, 256, 0, stream>>>(planes, pt);
        k_fused<true><<<nblocks, THREADS, 0, stream>>>(planes, pt, coords, depths,
                                                       w1, b1, w2, b2, out);
    } else {
        k_fused<false><<<nblocks, THREADS, 0, stream>>>(planes, nullptr, coords, depths,
                                                        w1, b1, w2, b2, out);
    }
}

// Round 4
// 227.081 us; speedup vs baseline: 1.5885x; 1.1626x over previous
//
#include <hip/hip_runtime.h>
#include <hip/hip_fp16.h>

#define NB 2
#define RAYS 4096
#define SAMP 96
#define CF 32
#define HID 64
#define HW 256

constexpr int M_TOTAL = NB * RAYS * SAMP;   // 786432 samples

typedef _Float16 f16x8 __attribute__((ext_vector_type(8)));
typedef float f32x4 __attribute__((ext_vector_type(4)));
typedef int i32x4 __attribute__((ext_vector_type(4)));

__device__ __forceinline__ float softplus_f(float z) {
    return fmaxf(z, 0.f) + __logf(1.f + __expf(-fabsf(z)));
}
__device__ __forceinline__ float sigmoid_f(float z) {
    return __fdividef(1.f, 1.f + __expf(-z));
}

// planes (N,3,C,H,W) f32  ->  pt (N*3, H, W, C) f16  (channel-interleaved)
__global__ __launch_bounds__(256)
void k_transpose(const float* __restrict__ src, __half2* __restrict__ dst) {
    int i = blockIdx.x * 256 + threadIdx.x;   // over 6*65536*16 half2 outputs
    int c2 = i & 15;
    int xy = (i >> 4) & 0xFFFF;
    int pn = i >> 20;                          // n*3+p  in [0,6)
    const float* s = src + (((size_t)(pn * CF + c2 * 2)) << 16) + xy;
    float a = s[0];
    float b = s[(size_t)1 << 16];
    dst[((size_t)(pn) << 16) * 16 + (size_t)xy * 16 + c2] = __floats2half2_rn(a, b);
}

// ======================= split path: gather + MLP =======================
constexpr int SLICE_A = 9216;   // per-wave LDS slice bytes
constexpr int SIGO = 5120;      // sigma region within slice (float[64])
// xS / rgb rows: row*80 (+ c*16 / + c*2);  hS rows: row*144

__global__ __launch_bounds__(256)
void k_gmlp(const __half2* __restrict__ pt, const float* __restrict__ coords,
            const float* __restrict__ w1, const float* __restrict__ b1,
            const float* __restrict__ w2, const float* __restrict__ b2,
            __half* __restrict__ rgbW, float* __restrict__ sigW)
{
    __shared__ __align__(16) char sm[4 * SLICE_A];   // 36 KB -> 4 blocks/CU
    const int t = threadIdx.x;
    const int wv = t >> 6;                 // wave id 0..3
    const int l = t & 63;
    const int g = l >> 4;
    const int ln = l & 15;
    char* const slice = sm + wv * SLICE_A;

    const int msamp = blockIdx.x * 256 + t;
    const int nb = (msamp >= M_TOTAL / NB) ? 1 : 0;

    // ---- weight fragments in registers ----
    f16x8 b1f[4];
    float b1v[4];
    #pragma unroll
    for (int Nt = 0; Nt < 4; ++Nt) {
        const int hn = 16 * Nt + ln;
        const float4* p0 = (const float4*)(w1 + hn * CF + g * 8);
        float4 u = p0[0], v = p0[1];
        b1f[Nt][0] = (_Float16)u.x; b1f[Nt][1] = (_Float16)u.y;
        b1f[Nt][2] = (_Float16)u.z; b1f[Nt][3] = (_Float16)u.w;
        b1f[Nt][4] = (_Float16)v.x; b1f[Nt][5] = (_Float16)v.y;
        b1f[Nt][6] = (_Float16)v.z; b1f[Nt][7] = (_Float16)v.w;
        b1v[Nt] = b1[hn];
    }
    f16x8 b2f[3][2];
    float b2v[3];
    #pragma unroll
    for (int Nt2 = 0; Nt2 < 3; ++Nt2) {
        const int o = 16 * Nt2 + ln;
        if (o < 33) {
            #pragma unroll
            for (int kh = 0; kh < 2; ++kh) {
                const float4* p0 = (const float4*)(w2 + o * HID + kh * 32 + g * 8);
                float4 u = p0[0], v = p0[1];
                b2f[Nt2][kh][0] = (_Float16)u.x; b2f[Nt2][kh][1] = (_Float16)u.y;
                b2f[Nt2][kh][2] = (_Float16)u.z; b2f[Nt2][kh][3] = (_Float16)u.w;
                b2f[Nt2][kh][4] = (_Float16)v.x; b2f[Nt2][kh][5] = (_Float16)v.y;
                b2f[Nt2][kh][6] = (_Float16)v.z; b2f[Nt2][kh][7] = (_Float16)v.w;
            }
            b2v[Nt2] = b2[o];
        } else {
            #pragma unroll
            for (int kh = 0; kh < 2; ++kh)
                #pragma unroll
                for (int i = 0; i < 8; ++i) b2f[Nt2][kh][i] = (_Float16)0.f;
            b2v[Nt2] = 0.f;
        }
    }

    // ---- gather ----
    const float* cp = coords + (size_t)msamp * 3;
    const float c0 = cp[0], c1 = cp[1], c2v = cp[2];

    __half2 acc[16];
    #pragma unroll
    for (int k = 0; k < 16; ++k) acc[k] = __float2half2_rn(0.f);

    #pragma unroll
    for (int p = 0; p < 3; ++p) {
        const float u = (p == 2) ? c2v : c0;
        const float v = (p == 0) ? c1 : ((p == 1) ? c2v : c0);
        const float xf = fmaf(u, 128.f, 127.5f);
        const float yf = fmaf(v, 128.f, 127.5f);
        const float x0f = floorf(xf), y0f = floorf(yf);
        const float wx = xf - x0f, wy = yf - y0f;
        const int x0 = (int)x0f, y0 = (int)y0f;
        const float vx0 = (x0 >= 0 && x0 < HW) ? 1.f : 0.f;
        const float vx1 = (x0 + 1 >= 0 && x0 + 1 < HW) ? 1.f : 0.f;
        const float vy0 = (y0 >= 0 && y0 < HW) ? 1.f : 0.f;
        const float vy1 = (y0 + 1 >= 0 && y0 + 1 < HW) ? 1.f : 0.f;
        const int xc0 = min(max(x0, 0), HW - 1), xc1 = min(max(x0 + 1, 0), HW - 1);
        const int yc0 = min(max(y0, 0), HW - 1), yc1 = min(max(y0 + 1, 0), HW - 1);
        const float w00 = (1.f - wx) * (1.f - wy) * vx0 * vy0;
        const float w10 = wx * (1.f - wy) * vx1 * vy0;
        const float w01 = (1.f - wx) * wy * vx0 * vy1;
        const float w11 = wx * wy * vx1 * vy1;

        const __half2* pb = pt + ((size_t)(nb * 3 + p) << 16) * 16;
        auto tap = [&](int yc, int xc, float w) {
            const float4* tp = (const float4*)(pb + (size_t)(yc * HW + xc) * 16);
            const __half2 wh = __float2half2_rn(w);
            #pragma unroll
            for (int q = 0; q < 4; ++q) {
                union { float4 f; __half2 h[4]; } u4;
                u4.f = tp[q];
                acc[q * 4 + 0] = __hfma2(wh, u4.h[0], acc[q * 4 + 0]);
                acc[q * 4 + 1] = __hfma2(wh, u4.h[1], acc[q * 4 + 1]);
                acc[q * 4 + 2] = __hfma2(wh, u4.h[2], acc[q * 4 + 2]);
                acc[q * 4 + 3] = __hfma2(wh, u4.h[3], acc[q * 4 + 3]);
            }
        };
        tap(yc0, xc0, w00);
        tap(yc0, xc1, w10);
        tap(yc1, xc0, w01);
        tap(yc1, xc1, w11);
    }

    // ---- stage x ----
    const __half2 third = __float2half2_rn(1.f / 3.f);
    #pragma unroll
    for (int c = 0; c < 4; ++c) {
        union { __half2 h[4]; i32x4 v; } u4;
        #pragma unroll
        for (int j = 0; j < 4; ++j) u4.h[j] = __hmul2(acc[4 * c + j], third);
        *(i32x4*)(slice + l * 80 + c * 16) = u4.v;
    }

    // ---- layer 1 ----
    f16x8 a1[4];
    #pragma unroll
    for (int Mt = 0; Mt < 4; ++Mt)
        a1[Mt] = *(const f16x8*)(slice + (16 * Mt + ln) * 80 + g * 16);

    constexpr float is32 = 0.17677669529663687f;
    #pragma unroll
    for (int Nt = 0; Nt < 4; ++Nt) {
        f32x4 d0 = {0.f, 0.f, 0.f, 0.f};
        f32x4 d1 = {0.f, 0.f, 0.f, 0.f};
        f32x4 d2 = {0.f, 0.f, 0.f, 0.f};
        f32x4 d3 = {0.f, 0.f, 0.f, 0.f};
        d0 = __builtin_amdgcn_mfma_f32_16x16x32_f16(a1[0], b1f[Nt], d0, 0, 0, 0);
        d1 = __builtin_amdgcn_mfma_f32_16x16x32_f16(a1[1], b1f[Nt], d1, 0, 0, 0);
        d2 = __builtin_amdgcn_mfma_f32_16x16x32_f16(a1[2], b1f[Nt], d2, 0, 0, 0);
        d3 = __builtin_amdgcn_mfma_f32_16x16x32_f16(a1[3], b1f[Nt], d3, 0, 0, 0);
        const int hcol = 16 * Nt + ln;
        #pragma unroll
        for (int Mt = 0; Mt < 4; ++Mt) {
            f32x4 dd = (Mt == 0) ? d0 : (Mt == 1) ? d1 : (Mt == 2) ? d2 : d3;
            #pragma unroll
            for (int r = 0; r < 4; ++r) {
                const float hv = softplus_f(fmaf(dd[r], is32, b1v[Nt]));
                const int row = 16 * Mt + 4 * g + r;
                *(__half*)(slice + row * 144 + hcol * 2) = __float2half(hv);
            }
        }
    }

    // ---- layer 2 ----
    f16x8 a2[4][2];
    #pragma unroll
    for (int Mt = 0; Mt < 4; ++Mt)
        #pragma unroll
        for (int kh = 0; kh < 2; ++kh)
            a2[Mt][kh] = *(const f16x8*)(slice + (16 * Mt + ln) * 144 + (kh * 4 + g) * 16);

    #pragma unroll
    for (int Nt2 = 0; Nt2 < 3; ++Nt2) {
        f32x4 e0 = {0.f, 0.f, 0.f, 0.f};
        f32x4 e1 = {0.f, 0.f, 0.f, 0.f};
        f32x4 e2 = {0.f, 0.f, 0.f, 0.f};
        f32x4 e3 = {0.f, 0.f, 0.f, 0.f};
        #pragma unroll
        for (int kh = 0; kh < 2; ++kh) {
            e0 = __builtin_amdgcn_mfma_f32_16x16x32_f16(a2[0][kh], b2f[Nt2][kh], e0, 0, 0, 0);
            e1 = __builtin_amdgcn_mfma_f32_16x16x32_f16(a2[1][kh], b2f[Nt2][kh], e1, 0, 0, 0);
            e2 = __builtin_amdgcn_mfma_f32_16x16x32_f16(a2[2][kh], b2f[Nt2][kh], e2, 0, 0, 0);
            e3 = __builtin_amdgcn_mfma_f32_16x16x32_f16(a2[3][kh], b2f[Nt2][kh], e3, 0, 0, 0);
        }
        const int o = 16 * Nt2 + ln;
        if (o == 0) {
            #pragma unroll
            for (int Mt = 0; Mt < 4; ++Mt) {
                f32x4 ee = (Mt == 0) ? e0 : (Mt == 1) ? e1 : (Mt == 2) ? e2 : e3;
                #pragma unroll
                for (int r = 0; r < 4; ++r) {
                    const int row = 16 * Mt + 4 * g + r;
                    *(float*)(slice + SIGO + row * 4) = fmaf(ee[r], 0.125f, b2v[0]);
                }
            }
        } else if (o < 33) {
            #pragma unroll
            for (int Mt = 0; Mt < 4; ++Mt) {
                f32x4 ee = (Mt == 0) ? e0 : (Mt == 1) ? e1 : (Mt == 2) ? e2 : e3;
                #pragma unroll
                for (int r = 0; r < 4; ++r) {
                    const float vv = fmaf(ee[r], 0.125f, b2v[Nt2]);
                    const float rr = sigmoid_f(vv) * 1.002f - 0.001f;
                    const int row = 16 * Mt + 4 * g + r;
                    *(__half*)(slice + row * 80 + (o - 1) * 2) = __float2half(rr);
                }
            }
        }
    }

    // ---- coalesced stores (nontemporal: keep L2 for the table) ----
    const int waveBase = blockIdx.x * 256 + wv * 64;
    const int q0 = l & 3, r0 = l >> 2;
    #pragma unroll
    for (int q = 0; q < 4; ++q) {
        const int row = 16 * q + r0;
        i32x4 v = *(const i32x4*)(slice + row * 80 + q0 * 16);
        __builtin_nontemporal_store(v,
            (i32x4*)((char*)rgbW + (size_t)(waveBase + row) * 64 + q0 * 16));
    }
    const float sv = *(const float*)(slice + SIGO + l * 4);
    __builtin_nontemporal_store(sv, sigW + waveBase + l);
}

// ======================= split path: composite =======================
__global__ __launch_bounds__(512)
void k_comp(const __half* __restrict__ rgbW, const float* __restrict__ sigW,
            const float* __restrict__ depths, float* __restrict__ out)
{
    __shared__ float sgS[16 * SAMP];
    __shared__ float dpS[16 * SAMP];
    const int t = threadIdx.x;
    const int rayBase = blockIdx.x * 16;
    for (int i = t; i < 16 * SAMP; i += 512) {
        sgS[i] = sigW[(size_t)rayBase * SAMP + i];
        dpS[i] = depths[(size_t)rayBase * SAMP + i];
    }
    __syncthreads();

    const int rs = t >> 5;          // ray slot 0..15
    const int c = t & 31;           // channel
    const size_t mb = (size_t)(rayBase + rs) * SAMP;
    const ushort* rgbU = (const ushort*)rgbW;

    auto ldr = [&](size_t idx) -> float {
        ushort u = __builtin_nontemporal_load(rgbU + idx);
        __half h = *(__half*)&u;
        return __half2float(h);
    };

    float T = 1.f, a_out = 0.f;
    float sp = sgS[rs * SAMP], dp = dpS[rs * SAMP];
    float rp = ldr(mb * 32 + c);
    float rnx = ldr((mb + 1) * 32 + c);
    #pragma unroll 2
    for (int ss = 1; ss < SAMP; ++ss) {
        const float rc = rnx;
        const int nxt = (ss + 1 < SAMP) ? (ss + 1) : (SAMP - 1);
        rnx = ldr((mb + nxt) * 32 + c);
        const float sc = sgS[rs * SAMP + ss];
        const float dc = dpS[rs * SAMP + ss];
        const float dens = softplus_f(0.5f * (sp + sc) - 1.f);
        const float alpha = 1.f - __expf(-(dc - dp) * dens);
        a_out = fmaf(alpha * T, 0.5f * (rp + rc), a_out);
        T *= 1.f - alpha + 1e-10f;
        sp = sc; dp = dc; rp = rc;
    }
    out[(size_t)(rayBase + rs) * CF + c] = fmaf(a_out, 2.f, -1.f);
}

// ======================= fallback: round-2 fused kernel =======================
constexpr int THREADS = 384;
constexpr int SLICE = 9216;
constexpr int SIG_OFF = 5120;
constexpr int DEP_OFF = 5376;

template<bool USE_WS>
__global__ __launch_bounds__(THREADS)
void k_fused(const float* __restrict__ planes, const __half2* __restrict__ pt,
             const float* __restrict__ coords, const float* __restrict__ depths,
             const float* __restrict__ w1, const float* __restrict__ b1,
             const float* __restrict__ w2, const float* __restrict__ b2,
             float* __restrict__ out)
{
    __shared__ __align__(16) char sm[6 * SLICE];
    const int t = threadIdx.x;
    const int wv = t >> 6;
    const int l = t & 63;
    const int g = l >> 4;
    const int ln = l & 15;
    char* const slice = sm + wv * SLICE;

    const int msamp = blockIdx.x * THREADS + t;
    const int nb = (blockIdx.x >= (NB * RAYS / 4 / 2)) ? 1 : 0;

    f16x8 b1f[4];
    float b1v[4];
    #pragma unroll
    for (int Nt = 0; Nt < 4; ++Nt) {
        const int hn = 16 * Nt + ln;
        const float4* p0 = (const float4*)(w1 + hn * CF + g * 8);
        float4 u = p0[0], v = p0[1];
        b1f[Nt][0] = (_Float16)u.x; b1f[Nt][1] = (_Float16)u.y;
        b1f[Nt][2] = (_Float16)u.z; b1f[Nt][3] = (_Float16)u.w;
        b1f[Nt][4] = (_Float16)v.x; b1f[Nt][5] = (_Float16)v.y;
        b1f[Nt][6] = (_Float16)v.z; b1f[Nt][7] = (_Float16)v.w;
        b1v[Nt] = b1[hn];
    }
    f16x8 b2f[3][2];
    float b2v[3];
    #pragma unroll
    for (int Nt2 = 0; Nt2 < 3; ++Nt2) {
        const int o = 16 * Nt2 + ln;
        if (o < 33) {
            #pragma unroll
            for (int kh = 0; kh < 2; ++kh) {
                const float4* p0 = (const float4*)(w2 + o * HID + kh * 32 + g * 8);
                float4 u = p0[0], v = p0[1];
                b2f[Nt2][kh][0] = (_Float16)u.x; b2f[Nt2][kh][1] = (_Float16)u.y;
                b2f[Nt2][kh][2] = (_Float16)u.z; b2f[Nt2][kh][3] = (_Float16)u.w;
                b2f[Nt2][kh][4] = (_Float16)v.x; b2f[Nt2][kh][5] = (_Float16)v.y;
                b2f[Nt2][kh][6] = (_Float16)v.z; b2f[Nt2][kh][7] = (_Float16)v.w;
            }
            b2v[Nt2] = b2[o];
        } else {
            #pragma unroll
            for (int kh = 0; kh < 2; ++kh)
                #pragma unroll
                for (int i = 0; i < 8; ++i) b2f[Nt2][kh][i] = (_Float16)0.f;
            b2v[Nt2] = 0.f;
        }
    }

    const float* cp = coords + (size_t)msamp * 3;
    const float c0 = cp[0], c1 = cp[1], c2v = cp[2];
    const float myDep = depths[msamp];

    __half2 acc[16];
    #pragma unroll
    for (int k = 0; k < 16; ++k) acc[k] = __float2half2_rn(0.f);
    float xf32[CF];
    if constexpr (!USE_WS) {
        #pragma unroll
        for (int c = 0; c < CF; ++c) xf32[c] = 0.f;
    }

    #pragma unroll
    for (int p = 0; p < 3; ++p) {
        const float u = (p == 2) ? c2v : c0;
        const float v = (p == 0) ? c1 : ((p == 1) ? c2v : c0);
        const float xf = fmaf(u, 128.f, 127.5f);
        const float yf = fmaf(v, 128.f, 127.5f);
        const float x0f = floorf(xf), y0f = floorf(yf);
        const float wx = xf - x0f, wy = yf - y0f;
        const int x0 = (int)x0f, y0 = (int)y0f;
        const float vx0 = (x0 >= 0 && x0 < HW) ? 1.f : 0.f;
        const float vx1 = (x0 + 1 >= 0 && x0 + 1 < HW) ? 1.f : 0.f;
        const float vy0 = (y0 >= 0 && y0 < HW) ? 1.f : 0.f;
        const float vy1 = (y0 + 1 >= 0 && y0 + 1 < HW) ? 1.f : 0.f;
        const int xc0 = min(max(x0, 0), HW - 1), xc1 = min(max(x0 + 1, 0), HW - 1);
        const int yc0 = min(max(y0, 0), HW - 1), yc1 = min(max(y0 + 1, 0), HW - 1);
        const float w00 = (1.f - wx) * (1.f - wy) * vx0 * vy0;
        const float w10 = wx * (1.f - wy) * vx1 * vy0;
        const float w01 = (1.f - wx) * wy * vx0 * vy1;
        const float w11 = wx * wy * vx1 * vy1;

        if constexpr (USE_WS) {
            const __half2* pb = pt + ((size_t)(nb * 3 + p) << 16) * 16;
            auto tap = [&](int yc, int xc, float w) {
                const float4* tp = (const float4*)(pb + (size_t)(yc * HW + xc) * 16);
                const __half2 wh = __float2half2_rn(w);
                #pragma unroll
                for (int q = 0; q < 4; ++q) {
                    union { float4 f; __half2 h[4]; } u4;
                    u4.f = tp[q];
                    acc[q * 4 + 0] = __hfma2(wh, u4.h[0], acc[q * 4 + 0]);
                    acc[q * 4 + 1] = __hfma2(wh, u4.h[1], acc[q * 4 + 1]);
                    acc[q * 4 + 2] = __hfma2(wh, u4.h[2], acc[q * 4 + 2]);
                    acc[q * 4 + 3] = __hfma2(wh, u4.h[3], acc[q * 4 + 3]);
                }
            };
            tap(yc0, xc0, w00);
            tap(yc0, xc1, w10);
            tap(yc1, xc0, w01);
            tap(yc1, xc1, w11);
        } else {
            const float* pb = planes + (((size_t)(nb * 3 + p) * CF) << 16);
            const int i00 = yc0 * HW + xc0, i10 = yc0 * HW + xc1;
            const int i01 = yc1 * HW + xc0, i11 = yc1 * HW + xc1;
            #pragma unroll
            for (int c = 0; c < CF; ++c) {
                const float* pc = pb + ((size_t)c << 16);
                float a0 = fmaf(w00, pc[i00], fmaf(w10, pc[i10], 0.f));
                float a1 = fmaf(w01, pc[i01], fmaf(w11, pc[i11], 0.f));
                xf32[c] += a0 + a1;
            }
        }
    }
    if constexpr (!USE_WS) {
        #pragma unroll
        for (int k = 0; k < 16; ++k)
            acc[k] = __floats2half2_rn(xf32[2 * k], xf32[2 * k + 1]);
    }

    const __half2 third = __float2half2_rn(1.f / 3.f);
    #pragma unroll
    for (int c = 0; c < 4; ++c) {
        union { __half2 h[4]; i32x4 v; } u4;
        #pragma unroll
        for (int j = 0; j < 4; ++j) u4.h[j] = __hmul2(acc[4 * c + j], third);
        *(i32x4*)(slice + l * 80 + c * 16) = u4.v;
    }

    f16x8 a1[4];
    #pragma unroll
    for (int Mt = 0; Mt < 4; ++Mt)
        a1[Mt] = *(const f16x8*)(slice + (16 * Mt + ln) * 80 + g * 16);

    constexpr float is32 = 0.17677669529663687f;
    #pragma unroll
    for (int Nt = 0; Nt < 4; ++Nt) {
        f32x4 d0 = {0.f, 0.f, 0.f, 0.f};
        f32x4 d1 = {0.f, 0.f, 0.f, 0.f};
        f32x4 d2 = {0.f, 0.f, 0.f, 0.f};
        f32x4 d3 = {0.f, 0.f, 0.f, 0.f};
        d0 = __builtin_amdgcn_mfma_f32_16x16x32_f16(a1[0], b1f[Nt], d0, 0, 0, 0);
        d1 = __builtin_amdgcn_mfma_f32_16x16x32_f16(a1[1], b1f[Nt], d1, 0, 0, 0);
        d2 = __builtin_amdgcn_mfma_f32_16x16x32_f16(a1[2], b1f[Nt], d2, 0, 0, 0);
        d3 = __builtin_amdgcn_mfma_f32_16x16x32_f16(a1[3], b1f[Nt], d3, 0, 0, 0);
        const int hcol = 16 * Nt + ln;
        #pragma unroll
        for (int Mt = 0; Mt < 4; ++Mt) {
            f32x4 dd = (Mt == 0) ? d0 : (Mt == 1) ? d1 : (Mt == 2) ? d2 : d3;
            #pragma unroll
            for (int r = 0; r < 4; ++r) {
                const float hv = softplus_f(fmaf(dd[r], is32, b1v[Nt]));
                const int row = 16 * Mt + 4 * g + r;
                *(__half*)(slice + row * 144 + hcol * 2) = __float2half(hv);
            }
        }
    }

    f16x8 a2[4][2];
    #pragma unroll
    for (int Mt = 0; Mt < 4; ++Mt)
        #pragma unroll
        for (int kh = 0; kh < 2; ++kh)
            a2[Mt][kh] = *(const f16x8*)(slice + (16 * Mt + ln) * 144 + (kh * 4 + g) * 16);

    *(float*)(slice + DEP_OFF + l * 4) = myDep;

    #pragma unroll
    for (int Nt2 = 0; Nt2 < 3; ++Nt2) {
        f32x4 e0 = {0.f, 0.f, 0.f, 0.f};
        f32x4 e1 = {0.f, 0.f, 0.f, 0.f};
        f32x4 e2 = {0.f, 0.f, 0.f, 0.f};
        f32x4 e3 = {0.f, 0.f, 0.f, 0.f};
        #pragma unroll
        for (int kh = 0; kh < 2; ++kh) {
            e0 = __builtin_amdgcn_mfma_f32_16x16x32_f16(a2[0][kh], b2f[Nt2][kh], e0, 0, 0, 0);
            e1 = __builtin_amdgcn_mfma_f32_16x16x32_f16(a2[1][kh], b2f[Nt2][kh], e1, 0, 0, 0);
            e2 = __builtin_amdgcn_mfma_f32_16x16x32_f16(a2[2][kh], b2f[Nt2][kh], e2, 0, 0, 0);
            e3 = __builtin_amdgcn_mfma_f32_16x16x32_f16(a2[3][kh], b2f[Nt2][kh], e3, 0, 0, 0);
        }
        const int o = 16 * Nt2 + ln;
        if (o == 0) {
            #pragma unroll
            for (int Mt = 0; Mt < 4; ++Mt) {
                f32x4 ee = (Mt == 0) ? e0 : (Mt == 1) ? e1 : (Mt == 2) ? e2 : e3;
                #pragma unroll
                for (int r = 0; r < 4; ++r) {
                    const int row = 16 * Mt + 4 * g + r;
                    *(float*)(slice + SIG_OFF + row * 4) = fmaf(ee[r], 0.125f, b2v[0]);
                }
            }
        } else if (o < 33) {
            #pragma unroll
            for (int Mt = 0; Mt < 4; ++Mt) {
                f32x4 ee = (Mt == 0) ? e0 : (Mt == 1) ? e1 : (Mt == 2) ? e2 : e3;
                #pragma unroll
                for (int r = 0; r < 4; ++r) {
                    const float vv = fmaf(ee[r], 0.125f, b2v[Nt2]);
                    const float rr = sigmoid_f(vv) * 1.002f - 0.001f;
                    const int row = 16 * Mt + 4 * g + r;
                    *(__half*)(slice + row * 80 + (o + 1) * 2) = __float2half(rr);
                }
            }
        }
    }

    __syncthreads();

    if (t < 128) {
        const int crl = t >> 5;
        const int c = t & 31;
        const int bs = crl * SAMP;
        auto sigAt = [&](int sb) -> float {
            return *(const float*)(sm + (sb >> 6) * SLICE + SIG_OFF + (sb & 63) * 4);
        };
        auto depAt = [&](int sb) -> float {
            return *(const float*)(sm + (sb >> 6) * SLICE + DEP_OFF + (sb & 63) * 4);
        };
        auto rgbAt = [&](int sb) -> float {
            return __half2float(*(const __half*)(sm + (sb >> 6) * SLICE + (sb & 63) * 80 + (c + 1) * 2));
        };
        float T = 1.f, a_out = 0.f;
        float sp = sigAt(bs), dp = depAt(bs), rp = rgbAt(bs);
        for (int ss = 1; ss < SAMP; ++ss) {
            const float sc = sigAt(bs + ss);
            const float dc = depAt(bs + ss);
            const float rc = rgbAt(bs + ss);
            const float dens = softplus_f(0.5f * (sp + sc) - 1.f);
            const float alpha = 1.f - __expf(-(dc - dp) * dens);
            a_out = fmaf(alpha * T, 0.5f * (rp + rc), a_out);
            T *= 1.f - alpha + 1e-10f;
            sp = sc; dp = dc; rp = rc;
        }
        out[(size_t)(blockIdx.x * 4 + crl) * CF + c] = fmaf(a_out, 2.f, -1.f);
    }
}

extern "C" void kernel_launch(void* const* d_in, const int* in_sizes, int n_in,
                              void* d_out, int out_size, void* d_ws, size_t ws_size,
                              hipStream_t stream) {
    (void)in_sizes; (void)n_in; (void)out_size;
    const float* planes = (const float*)d_in[0];
    const float* coords = (const float*)d_in[1];
    const float* depths = (const float*)d_in[2];
    const float* w1 = (const float*)d_in[3];
    const float* b1 = (const float*)d_in[4];
    const float* w2 = (const float*)d_in[5];
    const float* b2 = (const float*)d_in[6];
    float* out = (float*)d_out;

    const size_t ptBytes  = (size_t)NB * 3 * HW * HW * CF * sizeof(__half);   // 25.2 MB
    const size_t rgbBytes = (size_t)M_TOTAL * CF * sizeof(__half);            // 50.3 MB
    const size_t sigBytes = (size_t)M_TOTAL * sizeof(float);                  //  3.1 MB
    const int tgrid = NB * 3 * HW * HW * CF / 2 / 256;                        // 24576

    if (ws_size >= ptBytes + rgbBytes + sigBytes) {
        __half2* pt = (__half2*)d_ws;
        __half* rgbW = (__half*)((char*)d_ws + ptBytes);
        float* sigW = (float*)((char*)d_ws + ptBytes + rgbBytes);
        k_transpose<<<tgrid, 256, 0, stream>>>(planes, pt);
        k_gmlp<<<M_TOTAL / 256, 256, 0, stream>>>(pt, coords, w1, b1, w2, b2, rgbW, sigW);
        k_comp<<<NB * RAYS / 16, 512, 0, stream>>>(rgbW, sigW, depths, out);
    } else if (ws_size >= ptBytes) {
        __half2* pt = (__half2*)d_ws;
        k_transpose<<<tgrid, 256, 0, stream>>>(planes, pt);
        k_fused<true><<<M_TOTAL / THREADS, THREADS, 0, stream>>>(planes, pt, coords, depths,
                                                                 w1, b1, w2, b2, out);
    } else {
        k_fused<false><<<M_TOTAL / THREADS, THREADS, 0, stream>>>(planes, nullptr, coords, depths,
                                                                  w1, b1, w2, b2, out);
    }
}